// Round 19
// baseline (180.815 us; speedup 1.0000x reference)
//
#include <hip/hip_runtime.h>

#define BATCH 262144

typedef __attribute__((ext_vector_type(8))) short short8;
typedef __attribute__((ext_vector_type(4))) float f32x4;

static __device__ __forceinline__ unsigned cvtpk(float lo, float hi) {
    unsigned r;
    asm("v_cvt_pk_bf16_f32 %0, %1, %2" : "=v"(r) : "v"(lo), "v"(hi));
    return r;
}
// float -> bf16 bits (RNE) for the weight-prep kernel
static __device__ __forceinline__ unsigned short f2b(float f) {
    unsigned u = __float_as_uint(f);
    return (unsigned short)((u + 0x7fffu + ((u >> 16) & 1u)) >> 16);
}
static __device__ __forceinline__ float b2f(short s) {
    return __uint_as_float(((unsigned)(unsigned short)s) << 16);
}
static __device__ __forceinline__ float sigm(float x) { return 1.0f / (1.0f + __expf(-x)); }
static __device__ __forceinline__ float tanh_f(float x) { return 1.0f - 2.0f / (__expf(2.0f * x) + 1.0f); }

// LDS serves a wave's DS ops in program order; compiler-only barrier keeps
// instruction order (R15: verified correct, neutral vs lgkmcnt(0) drain).
#define WAVE_FENCE() asm volatile("" ::: "memory")

// XOR swizzle on 16B slots within a row (R4/R10-validated, <=2-way aliasing).
static __device__ __forceinline__ int sw128(int row, int cb) { return row * 128 + (cb ^ ((row & 7) << 4)); }
static __device__ __forceinline__ int sw256(int row, int cb) { return row * 256 + (cb ^ ((row & 7) << 4)); }

// bf16 weights flat in workspace (bytes): w1[0,16384) w2[16384,24576)
// wih[24576,49152) whh[49152,73728) lw1[73728,90112)
__global__ void prep_weights(const float* __restrict__ w1, const float* __restrict__ w2,
                             const float* __restrict__ wih, const float* __restrict__ whh,
                             const float* __restrict__ lw1, unsigned short* __restrict__ wsb) {
    int i = blockIdx.x * 256 + threadIdx.x;
    float v;
    if (i < 8192) v = w1[i];
    else if (i < 12288) v = w2[i - 8192];
    else if (i < 24576) v = wih[i - 12288];
    else if (i < 36864) v = whh[i - 24576];
    else if (i < 45056) v = lw1[i - 36864];
    else return;
    wsb[i] = f2b(v);
}

// R19: drop lw1 from LDS (stage-5 tail position -> its global latency overlaps
// the next tile's independent stage-0 gather). Weight LDS (swizzled):
//   w1 @0 [64][128]s256, w2 @16384 [64][64]s128, wih @24576 [192][64]s128,
//   whh @49152 [192][64]s128   = 73728 B
// 73728 + 14*6144 = 159744 <= 163840 -> 14 waves (3.5/SIMD, +17% vs R15).
#define WLDS_BYTES 73728
#define NCHUNK (WLDS_BYTES / 16)

// 896 threads = 14 waves; 1 block/CU (LDS-pinned). launch_bounds(896): reg cap
// 128 at 4 waves/SIMD — body needs ~88-96 (R15-identical), no forced squeeze.
// R16/R18 lesson: NO register row-prefetch, h stays in LDS.
__global__ __launch_bounds__(896) void tgn_kernel(
    const int* __restrict__ pairs, const float* __restrict__ memory,
    const unsigned short* __restrict__ wsb,
    const float* __restrict__ b1, const float* __restrict__ b2,
    const float* __restrict__ bih, const float* __restrict__ bhh,
    const float* __restrict__ lb1, const float* __restrict__ lw2,
    const float* __restrict__ lb2, float* __restrict__ out)
{
    __shared__ __align__(16) char wlds[WLDS_BYTES];  // w1|w2|wih|whh swizzled
    __shared__ __align__(16) char work[14][6144];    // per-wave: n1(2K) n2(2K) h1==msg(2K)

    const int tid = threadIdx.x;
    const int w  = tid >> 6;
    const int l  = tid & 63;
    const int lr = l & 15;       // M/N index within fragment
    const int lg = l >> 4;       // k-group / row-group

    // ---- stage weights once: global bytes [0,73728) -> LDS (swizzled) ----
    for (int c = tid; c < NCHUNK; c += 896) {
        int byte = c * 16;
        int base, sh;
        if (byte < 16384)      { base = 0;     sh = 8; }   // w1, 256B rows
        else if (byte < 24576) { base = 16384; sh = 7; }   // w2, 128B rows
        else if (byte < 49152) { base = 24576; sh = 7; }   // wih
        else                   { base = 49152; sh = 7; }   // whh
        int t   = byte - base;
        int row = t >> sh;
        int dst = base + (t ^ ((row & 7) << 4));
        *(short8*)(wlds + dst) = *(const short8*)((const char*)wsb + byte);
    }
    __syncthreads();   // weights visible to all waves (only block barrier)

    char* n1b = &work[w][0];     // [16][64] bf16 sw128; later comb c1 overlay
    char* n2b = &work[w][2048];  // [16][64] bf16 sw128; later comb c2 overlay
    char* hmb = &work[w][4096];  // h1, then msg (stage-2 reads precede writes)

    const char* w1l  = wlds + 0;      // [64][128] s256
    const char* w2l  = wlds + 16384;  // [64][64]  s128
    const char* wihl = wlds + 24576;  // [192][64] s128
    const char* whhl = wlds + 49152;  // [192][64] s128
    const unsigned short* lw1g = wsb + 36864;  // [64][128] GLOBAL (L2-resident 16KB)

    const f32x4 z4 = {0.0f, 0.0f, 0.0f, 0.0f};

    const int waveid = blockIdx.x * 14 + w;   // 0..3583

    // pairs prefetch: 4x int2 = 8 VGPRs live across the body
    int2 pr[4];
#pragma unroll
    for (int rr = 0; rr < 4; ++rr)
        pr[rr] = *(const int2*)(pairs + (waveid * 16 + rr * 4 + lg) * 2);

#pragma unroll 1   // one body copy: I$-hot across iterations
    for (int tile = waveid; tile < 16384; tile += 3584) {
        const int r0 = tile * 16;

        // ---- stage 0: gather rows (pairs resident) -> bf16 LDS ----
#pragma unroll
        for (int rr = 0; rr < 4; ++rr) {
            int row = rr * 4 + lg;
            f32x4 v1 = *(const f32x4*)(memory + (long)pr[rr].x * 64 + lr * 4);
            f32x4 v2 = *(const f32x4*)(memory + (long)pr[rr].y * 64 + lr * 4);
            uint2 c1v, c2v;
            c1v.x = cvtpk(v1[0], v1[1]); c1v.y = cvtpk(v1[2], v1[3]);
            c2v.x = cvtpk(v2[0], v2[1]); c2v.y = cvtpk(v2[2], v2[3]);
            int off = sw128(row, lr * 8);
            *(uint2*)(n1b + off) = c1v;
            *(uint2*)(n2b + off) = c2v;
        }
        // prefetch next tile's pairs (uniform branch)
        {
            int next = tile + 3584;
            if (next < 16384) {
#pragma unroll
                for (int rr = 0; rr < 4; ++rr)
                    pr[rr] = *(const int2*)(pairs + (next * 16 + rr * 4 + lg) * 2);
            }
        }
        WAVE_FENCE();

        // ---- stage 1: H1 = relu(X @ w1^T + b1), X = [n1|n2] (16x128) ----
        f32x4 acc[4];
#pragma unroll
        for (int nt = 0; nt < 4; ++nt) acc[nt] = z4;
#pragma unroll
        for (int kt = 0; kt < 4; ++kt) {
            const char* base = (kt < 2) ? n1b : n2b;
            short8 a = *(const short8*)(base + sw128(lr, (kt & 1) * 64 + lg * 16));
#pragma unroll
            for (int nt = 0; nt < 4; ++nt) {
                short8 b = *(const short8*)(w1l + sw256(nt * 16 + lr, kt * 64 + lg * 16));
                acc[nt] = __builtin_amdgcn_mfma_f32_16x16x32_bf16(a, b, acc[nt], 0, 0, 0);
            }
        }
#pragma unroll
        for (int nt = 0; nt < 4; ++nt) {
            float bv = b1[nt * 16 + lr];
            unsigned p01 = cvtpk(fmaxf(acc[nt][0] + bv, 0.0f), fmaxf(acc[nt][1] + bv, 0.0f));
            unsigned p23 = cvtpk(fmaxf(acc[nt][2] + bv, 0.0f), fmaxf(acc[nt][3] + bv, 0.0f));
            int cb = nt * 32 + lr * 2;
            *(short*)(hmb + sw128(lg * 4 + 0, cb)) = (short)p01;
            *(short*)(hmb + sw128(lg * 4 + 1, cb)) = (short)(p01 >> 16);
            *(short*)(hmb + sw128(lg * 4 + 2, cb)) = (short)p23;
            *(short*)(hmb + sw128(lg * 4 + 3, cb)) = (short)(p23 >> 16);
        }
        WAVE_FENCE();

        // ---- stage 2: MSG = H1 @ w2^T + b2; msg overlays h1 ----
#pragma unroll
        for (int nt = 0; nt < 4; ++nt) acc[nt] = z4;
#pragma unroll
        for (int kt = 0; kt < 2; ++kt) {
            short8 a = *(const short8*)(hmb + sw128(lr, kt * 64 + lg * 16));
#pragma unroll
            for (int nt = 0; nt < 4; ++nt) {
                short8 b = *(const short8*)(w2l + sw128(nt * 16 + lr, kt * 64 + lg * 16));
                acc[nt] = __builtin_amdgcn_mfma_f32_16x16x32_bf16(a, b, acc[nt], 0, 0, 0);
            }
        }
#pragma unroll
        for (int nt = 0; nt < 4; ++nt) {
            float bv = b2[nt * 16 + lr];
            unsigned p01 = cvtpk(acc[nt][0] + bv, acc[nt][1] + bv);
            unsigned p23 = cvtpk(acc[nt][2] + bv, acc[nt][3] + bv);
            int cb = nt * 32 + lr * 2;
            *(short*)(hmb + sw128(lg * 4 + 0, cb)) = (short)p01;
            *(short*)(hmb + sw128(lg * 4 + 1, cb)) = (short)(p01 >> 16);
            *(short*)(hmb + sw128(lg * 4 + 2, cb)) = (short)p23;
            *(short*)(hmb + sw128(lg * 4 + 3, cb)) = (short)(p23 >> 16);
        }
        WAVE_FENCE();

        // ---- stage 3+4 fused: gates (LDS weights) + GRU; comb overlays n1/n2 ----
        short8 am[2], a1[2], a2[2];
#pragma unroll
        for (int kt = 0; kt < 2; ++kt) {
            am[kt] = *(const short8*)(hmb + sw128(lr, kt * 64 + lg * 16));
            a1[kt] = *(const short8*)(n1b + sw128(lr, kt * 64 + lg * 16));
            a2[kt] = *(const short8*)(n2b + sw128(lr, kt * 64 + lg * 16));
        }
#pragma unroll
        for (int nt = 0; nt < 4; ++nt) {
            f32x4 gir = z4, giz = z4, gin = z4;
            f32x4 g1r = z4, g1z = z4, g1n = z4;
            f32x4 g2r = z4, g2z = z4, g2n = z4;
#pragma unroll
            for (int kt = 0; kt < 2; ++kt) {
                int ko = kt * 64 + lg * 16;
                short8 bir = *(const short8*)(wihl + sw128((0 + nt) * 16 + lr, ko));
                short8 biz = *(const short8*)(wihl + sw128((4 + nt) * 16 + lr, ko));
                short8 bin = *(const short8*)(wihl + sw128((8 + nt) * 16 + lr, ko));
                short8 bhr = *(const short8*)(whhl + sw128((0 + nt) * 16 + lr, ko));
                short8 bhz = *(const short8*)(whhl + sw128((4 + nt) * 16 + lr, ko));
                short8 bhn = *(const short8*)(whhl + sw128((8 + nt) * 16 + lr, ko));
                gir = __builtin_amdgcn_mfma_f32_16x16x32_bf16(am[kt], bir, gir, 0, 0, 0);
                giz = __builtin_amdgcn_mfma_f32_16x16x32_bf16(am[kt], biz, giz, 0, 0, 0);
                gin = __builtin_amdgcn_mfma_f32_16x16x32_bf16(am[kt], bin, gin, 0, 0, 0);
                g1r = __builtin_amdgcn_mfma_f32_16x16x32_bf16(a1[kt], bhr, g1r, 0, 0, 0);
                g1z = __builtin_amdgcn_mfma_f32_16x16x32_bf16(a1[kt], bhz, g1z, 0, 0, 0);
                g1n = __builtin_amdgcn_mfma_f32_16x16x32_bf16(a1[kt], bhn, g1n, 0, 0, 0);
                g2r = __builtin_amdgcn_mfma_f32_16x16x32_bf16(a2[kt], bhr, g2r, 0, 0, 0);
                g2z = __builtin_amdgcn_mfma_f32_16x16x32_bf16(a2[kt], bhz, g2z, 0, 0, 0);
                g2n = __builtin_amdgcn_mfma_f32_16x16x32_bf16(a2[kt], bhn, g2n, 0, 0, 0);
            }
            int j = nt * 16 + lr;
            float bir_ = bih[j], biz_ = bih[64 + j], bin_ = bih[128 + j];
            float bhr_ = bhh[j], bhz_ = bhh[64 + j], bhn_ = bhh[128 + j];
            float o1[4], o2[4];
#pragma unroll
            for (int r = 0; r < 4; ++r) {
                int row = lg * 4 + r;
                float i_r = gir[r] + bir_;
                float i_z = giz[r] + biz_;
                float i_n = gin[r] + bin_;
                float rg = sigm(i_r + g1r[r] + bhr_);
                float zg = sigm(i_z + g1z[r] + bhz_);
                float ng = tanh_f(i_n + rg * (g1n[r] + bhn_));
                float h  = b2f(*(const short*)(n1b + sw128(row, j * 2)));
                o1[r] = (1.0f - zg) * ng + zg * h;
                rg = sigm(i_r + g2r[r] + bhr_);
                zg = sigm(i_z + g2z[r] + bhz_);
                ng = tanh_f(i_n + rg * (g2n[r] + bhn_));
                h  = b2f(*(const short*)(n2b + sw128(row, j * 2)));
                o2[r] = (1.0f - zg) * ng + zg * h;
            }
            unsigned q01 = cvtpk(o1[0], o1[1]), q23 = cvtpk(o1[2], o1[3]);
            unsigned s01 = cvtpk(o2[0], o2[1]), s23 = cvtpk(o2[2], o2[3]);
            *(short*)(n1b + sw128(lg * 4 + 0, j * 2)) = (short)q01;
            *(short*)(n1b + sw128(lg * 4 + 1, j * 2)) = (short)(q01 >> 16);
            *(short*)(n1b + sw128(lg * 4 + 2, j * 2)) = (short)q23;
            *(short*)(n1b + sw128(lg * 4 + 3, j * 2)) = (short)(q23 >> 16);
            *(short*)(n2b + sw128(lg * 4 + 0, j * 2)) = (short)s01;
            *(short*)(n2b + sw128(lg * 4 + 1, j * 2)) = (short)(s01 >> 16);
            *(short*)(n2b + sw128(lg * 4 + 2, j * 2)) = (short)s23;
            *(short*)(n2b + sw128(lg * 4 + 3, j * 2)) = (short)(s23 >> 16);
        }
        WAVE_FENCE();

        // ---- stage 5: H = relu(COMB @ lp_w1^T + lb1); lw1 from GLOBAL ----
        // (tail position: its ~200cy L2 latency overlaps next tile's gather)
        f32x4 acc5[4];
#pragma unroll
        for (int nt = 0; nt < 4; ++nt) acc5[nt] = z4;
#pragma unroll
        for (int kt = 0; kt < 4; ++kt) {
            const char* base = (kt < 2) ? n1b : n2b;
            short8 a = *(const short8*)(base + sw128(lr, (kt & 1) * 64 + lg * 16));
#pragma unroll
            for (int nt = 0; nt < 4; ++nt) {
                short8 b = *(const short8*)(lw1g + (nt * 16 + lr) * 128 + kt * 32 + lg * 8);
                acc5[nt] = __builtin_amdgcn_mfma_f32_16x16x32_bf16(a, b, acc5[nt], 0, 0, 0);
            }
        }

        // ---- stage 6: out = sigmoid(H @ lp_w2^T + lb2), reduce over 64 cols ----
        float part[4] = {0.0f, 0.0f, 0.0f, 0.0f};
#pragma unroll
        for (int nt = 0; nt < 4; ++nt) {
            float w2v = lw2[nt * 16 + lr];
            float bv  = lb1[nt * 16 + lr];
#pragma unroll
            for (int r = 0; r < 4; ++r)
                part[r] += fmaxf(acc5[nt][r] + bv, 0.0f) * w2v;
        }
        float lb2v = lb2[0];
#pragma unroll
        for (int r = 0; r < 4; ++r) {
            float p = part[r];
            p += __shfl_xor(p, 1);
            p += __shfl_xor(p, 2);
            p += __shfl_xor(p, 4);
            p += __shfl_xor(p, 8);
            if (lr == 0) out[r0 + lg * 4 + r] = sigm(p + lb2v);
        }
        // loop-top LDS writes are WAR-safe vs stage-5 reads: DS in-order per wave.
    }
}

extern "C" void kernel_launch(void* const* d_in, const int* in_sizes, int n_in,
                              void* d_out, int out_size, void* d_ws, size_t ws_size,
                              hipStream_t stream) {
    const int*   pairs  = (const int*)d_in[0];
    const float* memory = (const float*)d_in[1];
    const float* w1  = (const float*)d_in[2];
    const float* b1  = (const float*)d_in[3];
    const float* w2  = (const float*)d_in[4];
    const float* b2  = (const float*)d_in[5];
    const float* wih = (const float*)d_in[6];
    const float* whh = (const float*)d_in[7];
    const float* bih = (const float*)d_in[8];
    const float* bhh = (const float*)d_in[9];
    const float* lw1 = (const float*)d_in[10];
    const float* lb1 = (const float*)d_in[11];
    const float* lw2 = (const float*)d_in[12];
    const float* lb2 = (const float*)d_in[13];
    unsigned short* wsb = (unsigned short*)d_ws;

    prep_weights<<<176, 256, 0, stream>>>(w1, w2, wih, whh, lw1, wsb);
    // persistent: 256 blocks (1/CU), 14 waves each, grid-stride over 16384 tiles
    tgn_kernel<<<256, 896, 0, stream>>>(pairs, memory, wsb, b1, b2, bih, bhh,
                                        lb1, lw2, lb2, (float*)d_out);
}

// Round 20
// 105.560 us; speedup vs baseline: 1.7129x; 1.7129x over previous
//
#include <hip/hip_runtime.h>

#define BATCH 262144

typedef __attribute__((ext_vector_type(8))) short short8;
typedef __attribute__((ext_vector_type(4))) float f32x4;

static __device__ __forceinline__ unsigned cvtpk(float lo, float hi) {
    unsigned r;
    asm("v_cvt_pk_bf16_f32 %0, %1, %2" : "=v"(r) : "v"(lo), "v"(hi));
    return r;
}
static __device__ __forceinline__ float b2f(short s) {
    return __uint_as_float(((unsigned)(unsigned short)s) << 16);
}
static __device__ __forceinline__ float sigm(float x) { return 1.0f / (1.0f + __expf(-x)); }
static __device__ __forceinline__ float tanh_f(float x) { return 1.0f - 2.0f / (__expf(2.0f * x) + 1.0f); }

// LDS serves a wave's DS ops in program order; compiler-only barrier keeps
// instruction order (R15: verified correct, neutral vs lgkmcnt(0) drain).
#define WAVE_FENCE() asm volatile("" ::: "memory")

// XOR swizzle on 16B slots within a row (R4/R10-validated, <=2-way aliasing).
static __device__ __forceinline__ int sw128(int row, int cb) { return row * 128 + (cb ^ ((row & 7) << 4)); }
static __device__ __forceinline__ int sw256(int row, int cb) { return row * 256 + (cb ^ ((row & 7) << 4)); }

// Weight LDS (swizzled): w1 @0 [64][128]s256, w2 @16384 [64][64]s128,
// wih @24576 [192][64]s128, whh @49152 [192][64]s128, lw1 @73728 [64][128]s256
#define WLDS_BYTES 90112
#define NCHUNK (WLDS_BYTES / 16)

// 768 threads = 12 waves; LDS 90112 + 12*6144 = 163840 B = full 160 KiB pool
// -> 1 block/CU, 3 waves/SIMD. Plain launch bounds (R12/R14-proven no-spill).
// PERSISTENT grid=256: weights staged once/CU; pairs-only prefetch (8 VGPR).
// Spill ledger (R4,R6,R9,R11,R13,R16,R18,R19): the body has ~0 reg slack —
// no row prefetch, no forced launch-bounds, no 14/16-wave variants.
// R20: weights converted f32->bf16 DURING staging (prep_weights kernel
// deleted — saves a dependent launch; staging regs recycled before the loop).
__global__ __launch_bounds__(768) void tgn_kernel(
    const int* __restrict__ pairs, const float* __restrict__ memory,
    const float* __restrict__ w1g, const float* __restrict__ w2g,
    const float* __restrict__ wihg, const float* __restrict__ whhg,
    const float* __restrict__ lw1g,
    const float* __restrict__ b1, const float* __restrict__ b2,
    const float* __restrict__ bih, const float* __restrict__ bhh,
    const float* __restrict__ lb1, const float* __restrict__ lw2,
    const float* __restrict__ lb2, float* __restrict__ out)
{
    __shared__ __align__(16) char wlds[WLDS_BYTES];  // all 5 weight tiles, swizzled
    __shared__ __align__(16) char work[12][6144];    // per-wave: n1(2K) n2(2K) h1==msg(2K)

    const int tid = threadIdx.x;
    const int w  = tid >> 6;
    const int l  = tid & 63;
    const int lr = l & 15;       // M/N index within fragment
    const int lg = l >> 4;       // k-group / row-group

    // ---- stage weights once: f32 global -> bf16 LDS (swizzled), 8 elems/chunk.
    // All region boundaries are multiples of 8 elems -> one source per chunk.
    for (int c = tid; c < NCHUNK; c += 768) {
        int byte = c * 16;       // bf16 byte offset in wlds layout
        int e    = c * 8;        // bf16 element index
        const float* src;
        int base, sh;
        if (e < 8192)       { src = w1g  + e;         base = 0;     sh = 8; }
        else if (e < 12288) { src = w2g  + e - 8192;  base = 16384; sh = 7; }
        else if (e < 24576) { src = wihg + e - 12288; base = 24576; sh = 7; }
        else if (e < 36864) { src = whhg + e - 24576; base = 49152; sh = 7; }
        else                { src = lw1g + e - 36864; base = 73728; sh = 8; }
        f32x4 v0 = *(const f32x4*)src;
        f32x4 v1 = *(const f32x4*)(src + 4);
        union { unsigned u[4]; short8 s; } r;
        r.u[0] = cvtpk(v0[0], v0[1]); r.u[1] = cvtpk(v0[2], v0[3]);
        r.u[2] = cvtpk(v1[0], v1[1]); r.u[3] = cvtpk(v1[2], v1[3]);
        int t   = byte - base;
        int row = t >> sh;
        int dst = base + (t ^ ((row & 7) << 4));
        *(short8*)(wlds + dst) = r.s;
    }
    __syncthreads();   // weights visible to all waves (only block barrier)

    char* n1b = &work[w][0];     // [16][64] bf16 sw128; later comb c1 overlay
    char* n2b = &work[w][2048];  // [16][64] bf16 sw128; later comb c2 overlay
    char* hmb = &work[w][4096];  // h1, then msg (stage-2 reads precede writes)

    const char* w1l  = wlds + 0;      // [64][128] s256
    const char* w2l  = wlds + 16384;  // [64][64]  s128
    const char* wihl = wlds + 24576;  // [192][64] s128
    const char* whhl = wlds + 49152;  // [192][64] s128
    const char* lw1l = wlds + 73728;  // [64][128] s256

    const f32x4 z4 = {0.0f, 0.0f, 0.0f, 0.0f};

    const int waveid = blockIdx.x * 12 + w;   // 0..3071

    // pairs prefetch: 4x int2 = 8 VGPRs live across the body (NOT row data)
    int2 pr[4];
#pragma unroll
    for (int rr = 0; rr < 4; ++rr)
        pr[rr] = *(const int2*)(pairs + (waveid * 16 + rr * 4 + lg) * 2);

#pragma unroll 1   // one body copy: I$-hot across iterations
    for (int tile = waveid; tile < 16384; tile += 3072) {
        const int r0 = tile * 16;

        // ---- stage 0: gather rows (pairs already resident) -> bf16 LDS ----
#pragma unroll
        for (int rr = 0; rr < 4; ++rr) {
            int row = rr * 4 + lg;
            f32x4 v1 = *(const f32x4*)(memory + (long)pr[rr].x * 64 + lr * 4);
            f32x4 v2 = *(const f32x4*)(memory + (long)pr[rr].y * 64 + lr * 4);
            uint2 c1v, c2v;
            c1v.x = cvtpk(v1[0], v1[1]); c1v.y = cvtpk(v1[2], v1[3]);
            c2v.x = cvtpk(v2[0], v2[1]); c2v.y = cvtpk(v2[2], v2[3]);
            int off = sw128(row, lr * 8);
            *(uint2*)(n1b + off) = c1v;
            *(uint2*)(n2b + off) = c2v;
        }
        // prefetch next tile's pairs (uniform branch)
        {
            int next = tile + 3072;
            if (next < 16384) {
#pragma unroll
                for (int rr = 0; rr < 4; ++rr)
                    pr[rr] = *(const int2*)(pairs + (next * 16 + rr * 4 + lg) * 2);
            }
        }
        WAVE_FENCE();

        // ---- stage 1: H1 = relu(X @ w1^T + b1), X = [n1|n2] (16x128) ----
        f32x4 acc[4];
#pragma unroll
        for (int nt = 0; nt < 4; ++nt) acc[nt] = z4;
#pragma unroll
        for (int kt = 0; kt < 4; ++kt) {
            const char* base = (kt < 2) ? n1b : n2b;
            short8 a = *(const short8*)(base + sw128(lr, (kt & 1) * 64 + lg * 16));
#pragma unroll
            for (int nt = 0; nt < 4; ++nt) {
                short8 b = *(const short8*)(w1l + sw256(nt * 16 + lr, kt * 64 + lg * 16));
                acc[nt] = __builtin_amdgcn_mfma_f32_16x16x32_bf16(a, b, acc[nt], 0, 0, 0);
            }
        }
#pragma unroll
        for (int nt = 0; nt < 4; ++nt) {
            float bv = b1[nt * 16 + lr];
            unsigned p01 = cvtpk(fmaxf(acc[nt][0] + bv, 0.0f), fmaxf(acc[nt][1] + bv, 0.0f));
            unsigned p23 = cvtpk(fmaxf(acc[nt][2] + bv, 0.0f), fmaxf(acc[nt][3] + bv, 0.0f));
            int cb = nt * 32 + lr * 2;
            *(short*)(hmb + sw128(lg * 4 + 0, cb)) = (short)p01;
            *(short*)(hmb + sw128(lg * 4 + 1, cb)) = (short)(p01 >> 16);
            *(short*)(hmb + sw128(lg * 4 + 2, cb)) = (short)p23;
            *(short*)(hmb + sw128(lg * 4 + 3, cb)) = (short)(p23 >> 16);
        }
        WAVE_FENCE();

        // ---- stage 2: MSG = H1 @ w2^T + b2; msg overlays h1 ----
#pragma unroll
        for (int nt = 0; nt < 4; ++nt) acc[nt] = z4;
#pragma unroll
        for (int kt = 0; kt < 2; ++kt) {
            short8 a = *(const short8*)(hmb + sw128(lr, kt * 64 + lg * 16));
#pragma unroll
            for (int nt = 0; nt < 4; ++nt) {
                short8 b = *(const short8*)(w2l + sw128(nt * 16 + lr, kt * 64 + lg * 16));
                acc[nt] = __builtin_amdgcn_mfma_f32_16x16x32_bf16(a, b, acc[nt], 0, 0, 0);
            }
        }
#pragma unroll
        for (int nt = 0; nt < 4; ++nt) {
            float bv = b2[nt * 16 + lr];
            unsigned p01 = cvtpk(acc[nt][0] + bv, acc[nt][1] + bv);
            unsigned p23 = cvtpk(acc[nt][2] + bv, acc[nt][3] + bv);
            int cb = nt * 32 + lr * 2;
            *(short*)(hmb + sw128(lg * 4 + 0, cb)) = (short)p01;
            *(short*)(hmb + sw128(lg * 4 + 1, cb)) = (short)(p01 >> 16);
            *(short*)(hmb + sw128(lg * 4 + 2, cb)) = (short)p23;
            *(short*)(hmb + sw128(lg * 4 + 3, cb)) = (short)(p23 >> 16);
        }
        WAVE_FENCE();

        // ---- stage 3+4 fused: gates (LDS weights) + GRU; comb overlays n1/n2 ----
        short8 am[2], a1[2], a2[2];
#pragma unroll
        for (int kt = 0; kt < 2; ++kt) {
            am[kt] = *(const short8*)(hmb + sw128(lr, kt * 64 + lg * 16));
            a1[kt] = *(const short8*)(n1b + sw128(lr, kt * 64 + lg * 16));
            a2[kt] = *(const short8*)(n2b + sw128(lr, kt * 64 + lg * 16));
        }
#pragma unroll
        for (int nt = 0; nt < 4; ++nt) {
            f32x4 gir = z4, giz = z4, gin = z4;
            f32x4 g1r = z4, g1z = z4, g1n = z4;
            f32x4 g2r = z4, g2z = z4, g2n = z4;
#pragma unroll
            for (int kt = 0; kt < 2; ++kt) {
                int ko = kt * 64 + lg * 16;
                short8 bir = *(const short8*)(wihl + sw128((0 + nt) * 16 + lr, ko));
                short8 biz = *(const short8*)(wihl + sw128((4 + nt) * 16 + lr, ko));
                short8 bin = *(const short8*)(wihl + sw128((8 + nt) * 16 + lr, ko));
                short8 bhr = *(const short8*)(whhl + sw128((0 + nt) * 16 + lr, ko));
                short8 bhz = *(const short8*)(whhl + sw128((4 + nt) * 16 + lr, ko));
                short8 bhn = *(const short8*)(whhl + sw128((8 + nt) * 16 + lr, ko));
                gir = __builtin_amdgcn_mfma_f32_16x16x32_bf16(am[kt], bir, gir, 0, 0, 0);
                giz = __builtin_amdgcn_mfma_f32_16x16x32_bf16(am[kt], biz, giz, 0, 0, 0);
                gin = __builtin_amdgcn_mfma_f32_16x16x32_bf16(am[kt], bin, gin, 0, 0, 0);
                g1r = __builtin_amdgcn_mfma_f32_16x16x32_bf16(a1[kt], bhr, g1r, 0, 0, 0);
                g1z = __builtin_amdgcn_mfma_f32_16x16x32_bf16(a1[kt], bhz, g1z, 0, 0, 0);
                g1n = __builtin_amdgcn_mfma_f32_16x16x32_bf16(a1[kt], bhn, g1n, 0, 0, 0);
                g2r = __builtin_amdgcn_mfma_f32_16x16x32_bf16(a2[kt], bhr, g2r, 0, 0, 0);
                g2z = __builtin_amdgcn_mfma_f32_16x16x32_bf16(a2[kt], bhz, g2z, 0, 0, 0);
                g2n = __builtin_amdgcn_mfma_f32_16x16x32_bf16(a2[kt], bhn, g2n, 0, 0, 0);
            }
            int j = nt * 16 + lr;
            float bir_ = bih[j], biz_ = bih[64 + j], bin_ = bih[128 + j];
            float bhr_ = bhh[j], bhz_ = bhh[64 + j], bhn_ = bhh[128 + j];
            float o1[4], o2[4];
#pragma unroll
            for (int r = 0; r < 4; ++r) {
                int row = lg * 4 + r;
                float i_r = gir[r] + bir_;
                float i_z = giz[r] + biz_;
                float i_n = gin[r] + bin_;
                float rg = sigm(i_r + g1r[r] + bhr_);
                float zg = sigm(i_z + g1z[r] + bhz_);
                float ng = tanh_f(i_n + rg * (g1n[r] + bhn_));
                float h  = b2f(*(const short*)(n1b + sw128(row, j * 2)));
                o1[r] = (1.0f - zg) * ng + zg * h;
                rg = sigm(i_r + g2r[r] + bhr_);
                zg = sigm(i_z + g2z[r] + bhz_);
                ng = tanh_f(i_n + rg * (g2n[r] + bhn_));
                h  = b2f(*(const short*)(n2b + sw128(row, j * 2)));
                o2[r] = (1.0f - zg) * ng + zg * h;
            }
            unsigned q01 = cvtpk(o1[0], o1[1]), q23 = cvtpk(o1[2], o1[3]);
            unsigned s01 = cvtpk(o2[0], o2[1]), s23 = cvtpk(o2[2], o2[3]);
            *(short*)(n1b + sw128(lg * 4 + 0, j * 2)) = (short)q01;
            *(short*)(n1b + sw128(lg * 4 + 1, j * 2)) = (short)(q01 >> 16);
            *(short*)(n1b + sw128(lg * 4 + 2, j * 2)) = (short)q23;
            *(short*)(n1b + sw128(lg * 4 + 3, j * 2)) = (short)(q23 >> 16);
            *(short*)(n2b + sw128(lg * 4 + 0, j * 2)) = (short)s01;
            *(short*)(n2b + sw128(lg * 4 + 1, j * 2)) = (short)(s01 >> 16);
            *(short*)(n2b + sw128(lg * 4 + 2, j * 2)) = (short)s23;
            *(short*)(n2b + sw128(lg * 4 + 3, j * 2)) = (short)(s23 >> 16);
        }
        WAVE_FENCE();

        // ---- stage 5: H = relu(COMB @ lp_w1^T + lb1); comb = [c1|c2] ----
        f32x4 acc5[4];
#pragma unroll
        for (int nt = 0; nt < 4; ++nt) acc5[nt] = z4;
#pragma unroll
        for (int kt = 0; kt < 4; ++kt) {
            const char* base = (kt < 2) ? n1b : n2b;
            short8 a = *(const short8*)(base + sw128(lr, (kt & 1) * 64 + lg * 16));
#pragma unroll
            for (int nt = 0; nt < 4; ++nt) {
                short8 b = *(const short8*)(lw1l + sw256(nt * 16 + lr, kt * 64 + lg * 16));
                acc5[nt] = __builtin_amdgcn_mfma_f32_16x16x32_bf16(a, b, acc5[nt], 0, 0, 0);
            }
        }

        // ---- stage 6: out = sigmoid(H @ lp_w2^T + lb2), reduce over 64 cols ----
        float part[4] = {0.0f, 0.0f, 0.0f, 0.0f};
#pragma unroll
        for (int nt = 0; nt < 4; ++nt) {
            float w2v = lw2[nt * 16 + lr];
            float bv  = lb1[nt * 16 + lr];
#pragma unroll
            for (int r = 0; r < 4; ++r)
                part[r] += fmaxf(acc5[nt][r] + bv, 0.0f) * w2v;
        }
        float lb2v = lb2[0];
#pragma unroll
        for (int r = 0; r < 4; ++r) {
            float p = part[r];
            p += __shfl_xor(p, 1);
            p += __shfl_xor(p, 2);
            p += __shfl_xor(p, 4);
            p += __shfl_xor(p, 8);
            if (lr == 0) out[r0 + lg * 4 + r] = sigm(p + lb2v);
        }
        // loop-top LDS writes are WAR-safe vs stage-5 reads: DS in-order per wave.
    }
}

extern "C" void kernel_launch(void* const* d_in, const int* in_sizes, int n_in,
                              void* d_out, int out_size, void* d_ws, size_t ws_size,
                              hipStream_t stream) {
    const int*   pairs  = (const int*)d_in[0];
    const float* memory = (const float*)d_in[1];
    const float* w1  = (const float*)d_in[2];
    const float* b1  = (const float*)d_in[3];
    const float* w2  = (const float*)d_in[4];
    const float* b2  = (const float*)d_in[5];
    const float* wih = (const float*)d_in[6];
    const float* whh = (const float*)d_in[7];
    const float* bih = (const float*)d_in[8];
    const float* bhh = (const float*)d_in[9];
    const float* lw1 = (const float*)d_in[10];
    const float* lb1 = (const float*)d_in[11];
    const float* lw2 = (const float*)d_in[12];
    const float* lb2 = (const float*)d_in[13];

    // single kernel: weights converted f32->bf16 during per-block LDS staging
    tgn_kernel<<<256, 768, 0, stream>>>(pairs, memory, w1, w2, wih, whh, lw1,
                                        b1, b2, bih, bhh, lb1, lw2, lb2,
                                        (float*)d_out);
}